// Round 20
// baseline (96.792 us; speedup 1.0000x reference)
//
#include <hip/hip_runtime.h>
#include <hip/hip_bf16.h>
#include <math.h>

#define NN 8192
#define INF_ 128
#define OUTF 64

typedef __attribute__((ext_vector_type(4))) float f32x4;
typedef __attribute__((ext_vector_type(4))) int i32x4;
typedef __attribute__((ext_vector_type(8))) unsigned short u16x8;
typedef __attribute__((ext_vector_type(8))) __bf16 bf16x8;

// barrier WITHOUT vmcnt drain: LDS visibility only (lgkmcnt).
#define BAR()                                                    \
    {                                                            \
        asm volatile("s_waitcnt lgkmcnt(0)" ::: "memory");       \
        __builtin_amdgcn_s_barrier();                            \
    }

__device__ __forceinline__ unsigned short f2bf(float f) {
    unsigned int u = __float_as_uint(f);
    u = (u + 0x7FFFu + ((u >> 16) & 1u)) >> 16;
    return (unsigned short)u;
}

// ---- Kernel 1: Wh = h@W (fp32); f1 = Wh@a1; f2 = Wh@a2; WhT = bf16(Wh)^T [64][8192]
__global__ __launch_bounds__(256) void prep_kernel(
    const float* __restrict__ h, const float* __restrict__ W,
    const float* __restrict__ a, unsigned short* __restrict__ WhT,
    float* __restrict__ f1, float* __restrict__ f2)
{
    __shared__ float W_lds[INF_ * OUTF];
    __shared__ float h_lds[32 * INF_];
    __shared__ unsigned short t_lds[OUTF * 34];

    const int t = threadIdx.x;
    const int rb = blockIdx.x * 32;

    {
        const float4* Ws = (const float4*)W;
        float4* Wd = (float4*)W_lds;
        #pragma unroll
        for (int q = 0; q < 8; ++q) Wd[t + 256 * q] = Ws[t + 256 * q];
        const float4* hs = (const float4*)(h + (size_t)rb * INF_);
        float4* hd = (float4*)h_lds;
        #pragma unroll
        for (int q = 0; q < 4; ++q) hd[t + 256 * q] = hs[t + 256 * q];
    }
    __syncthreads();

    const int lane = t & 63;
    const int w = t >> 6;

    float acc[8];
    #pragma unroll
    for (int q = 0; q < 8; ++q) acc[q] = 0.f;
    for (int k = 0; k < INF_; ++k) {
        const float wv = W_lds[k * OUTF + lane];
        #pragma unroll
        for (int q = 0; q < 8; ++q)
            acc[q] = fmaf(h_lds[(w * 8 + q) * INF_ + k], wv, acc[q]);
    }

    const float a1 = a[lane];
    const float a2 = a[OUTF + lane];
    #pragma unroll
    for (int q = 0; q < 8; ++q) {
        float s1 = acc[q] * a1;
        float s2 = acc[q] * a2;
        #pragma unroll
        for (int m = 1; m < 64; m <<= 1) {
            s1 += __shfl_xor(s1, m, 64);
            s2 += __shfl_xor(s2, m, 64);
        }
        if (lane == 0) {
            f1[rb + w * 8 + q] = s1;
            f2[rb + w * 8 + q] = s2;
        }
        t_lds[lane * 34 + w * 8 + q] = f2bf(acc[q]);
    }
    __syncthreads();
    {
        const int c = t >> 2;
        const int ro = (t & 3) * 8;
        unsigned int pk[4];
        #pragma unroll
        for (int i = 0; i < 4; ++i) {
            const unsigned int lo = t_lds[c * 34 + ro + 2 * i];
            const unsigned int hi = t_lds[c * 34 + ro + 2 * i + 1];
            pk[i] = lo | (hi << 16);
        }
        *(uint4*)(WhT + (size_t)c * NN + rb + ro) = make_uint4(pk[0], pk[1], pk[2], pk[3]);
    }
}

// ---- Kernel 1b: f2max = max_j f2[j]
__global__ __launch_bounds__(1024) void fmax_kernel(
    const float* __restrict__ f2, float* __restrict__ f2max)
{
    __shared__ float red[16];
    const int t = threadIdx.x;
    float m = -INFINITY;
    #pragma unroll
    for (int q = 0; q < NN / 1024; ++q) m = fmaxf(m, f2[t + q * 1024]);
    #pragma unroll
    for (int s = 1; s < 64; s <<= 1) m = fmaxf(m, __shfl_xor(m, s, 64));
    if ((t & 63) == 0) red[t >> 6] = m;
    __syncthreads();
    if (t == 0) {
        float r = red[0];
        #pragma unroll
        for (int i = 1; i < 16; ++i) r = fmaxf(r, red[i]);
        f2max[0] = r;
    }
}

// ---- Kernel 1c: repack WhT into lane-contiguous B-fragments.
__global__ __launch_bounds__(256) void repack_kernel(
    const unsigned short* __restrict__ WhT, unsigned short* __restrict__ WhTs)
{
    const int ch = blockIdx.x;    // 256 chunks of 32 j
    const int t = threadIdx.x;
    const int qd = t >> 6, l = t & 63;
    const int r = l & 15, g = l >> 4;
    const u16x8 v = *(const u16x8*)(WhT + (size_t)(qd * 16 + r) * NN + ch * 32 + g * 8);
    *(u16x8*)(WhTs + (size_t)ch * 2048 + qd * 512 + l * 8) = v;
}

// ---- Kernel 1d: bd[j] = pack(bf16(exp(f2_j)), bf16(exp(0.2*f2_j)))
__global__ __launch_bounds__(1024) void bd_kernel(
    const float* __restrict__ f2, unsigned int* __restrict__ bd)
{
    const int i = blockIdx.x * 1024 + threadIdx.x;
    const float v = f2[i];
    const unsigned int B = f2bf(expf(v));
    const unsigned int D = f2bf(expf(0.2f * v));
    bd[i] = B | (D << 16);
}

// ---- Kernel 1e: bitpack adj -> 1 bit per entry (r3/r6-proven, plain loads).
// bits[row][byte b], bit i  <->  adj[row][8b+i] > 0
__global__ __launch_bounds__(256) void bitpack_kernel(
    const int* __restrict__ adj, unsigned char* __restrict__ bits)
{
    const int row = blockIdx.x;
    const int t = threadIdx.x;
    const int lane = t & 63;
    const int w = t >> 6;
    const int* src = adj + (size_t)row * NN + w * 2048;
    unsigned char* dst = bits + (size_t)row * (NN / 8) + w * 256;

    #pragma unroll
    for (int s = 0; s < 8; ++s) {
        const i32x4 v = *(const i32x4*)(src + s * 256 + 4 * lane);
        const unsigned long long b0 = __ballot(v[0] > 0); // bit l <-> j 4l+0
        const unsigned long long b1 = __ballot(v[1] > 0);
        const unsigned long long b2 = __ballot(v[2] > 0);
        const unsigned long long b3 = __ballot(v[3] > 0);
        if (lane < 32) {
            const unsigned int sh = 2 * lane;
            unsigned int B =
                ((unsigned int)(b0 >> sh) & 1u)        |
                (((unsigned int)(b1 >> sh) & 1u) << 1) |
                (((unsigned int)(b2 >> sh) & 1u) << 2) |
                (((unsigned int)(b3 >> sh) & 1u) << 3) |
                (((unsigned int)(b0 >> (sh + 1)) & 1u) << 4) |
                (((unsigned int)(b1 >> (sh + 1)) & 1u) << 5) |
                (((unsigned int)(b2 >> (sh + 1)) & 1u) << 6) |
                (((unsigned int)(b3 >> (sh + 1)) & 1u) << 7);
            dst[s * 32 + lane] = (unsigned char)B; // byte l covers j [8l,8l+8)
        }
    }
}

// ---- Kernel 2: consumer (r14 structure, ballot-free). Per wave: load row r's
//      1024 mask bits ONCE (km[16] u64), then 32 chunks of table-softmax+MFMA.
//      Loop VMEM = wq (L2) only -> no queue poisoning, no barriers in loop.
__global__ __launch_bounds__(512) void gatb_kernel(
    const unsigned char* __restrict__ bits, const unsigned short* __restrict__ WhTs,
    const float* __restrict__ f1, const unsigned int* __restrict__ bd,
    const float* __restrict__ f2max, float* __restrict__ out)
{
    __shared__ float acc_lds[8 * 16 * OUTF];  // 32 KB partials
    __shared__ unsigned int bd_lds[NN];       // 32 KB (B,D) bf16 pairs
    __shared__ float l_lds[8 * 16];

    const int t = threadIdx.x;
    const int lane = t & 63;
    const int w = t >> 6;
    const int r = lane & 15;     // A-frag row / D feature
    const int g = lane >> 4;     // k-group
    const int row_base = blockIdx.x * 16;

    // stage bd (32 KB) cooperatively
    #pragma unroll
    for (int q = 0; q < 4; ++q)
        ((uint4*)bd_lds)[t + 512 * q] = ((const uint4*)bd)[t + 512 * q];

    // load row r's mask slice for this wave's j-window [w*1024, +1024): 128 B
    // bit for j = ch*32+g*8+i  ->  km[cl>>1] bit (8g + 32*(cl&1) + i), cl=ch-w*32
    unsigned long long km[16];
    {
        const unsigned long long* kmp = (const unsigned long long*)
            (bits + (size_t)(row_base + r) * (NN / 8) + w * 128);
        #pragma unroll
        for (int u = 0; u < 16; ++u) km[u] = kmp[u];
    }

    const float f1r = f1[row_base + r];
    float Mr = f1r + f2max[0];
    Mr = fmaxf(Mr, 0.2f * Mr);
    const float A = expf(f1r - Mr);          // e>0 branch row factor
    const float C = expf(0.2f * f1r - Mr);   // e<=0 branch row factor
    const unsigned int THb = (unsigned int)f2bf(expf(-f1r)); // B_j > THb <=> e>0
    const unsigned int sh8g = 8u * (unsigned int)g;

    f32x4 accl = {0.f, 0.f, 0.f, 0.f};
    f32x4 acc[4];
    #pragma unroll
    for (int q = 0; q < 4; ++q) acc[q] = accl;

    u16x8 ones_u;
    #pragma unroll
    for (int i = 0; i < 8; ++i) ones_u[i] = 0x3F80;
    const bf16x8 bones = __builtin_bit_cast(bf16x8, ones_u);

    BAR(); // bd_lds visible

    {
        const u16x8* wv = (const u16x8*)WhTs + lane; // + (ch*4+qd)*64
        const int chb = w * 32;

        #pragma unroll
        for (int cl = 0; cl < 32; ++cl) {
            const int ch = chb + cl;
            const int col = ch * 32 + g * 8;

            // this chunk's 4 B-fragment loads (the loop's only VMEM)
            u16x8 wq[4];
            #pragma unroll
            for (int qd = 0; qd < 4; ++qd)
                wq[qd] = wv[((size_t)ch * 4 + qd) * 64];

            const unsigned long long kmv = km[cl >> 1];
            const unsigned int bsh = sh8g + ((cl & 1) << 5);

            const uint4 bq0 = *(const uint4*)(bd_lds + col);
            const uint4 bq1 = *(const uint4*)(bd_lds + col + 4);
            const unsigned int bdv[8] = {bq0.x, bq0.y, bq0.z, bq0.w,
                                         bq1.x, bq1.y, bq1.z, bq1.w};

            u16x8 pb;
            #pragma unroll
            for (int i = 0; i < 8; ++i) {
                const unsigned int v = bdv[i];
                const unsigned int bb = v & 0xFFFFu;
                const bool up = bb > THb;                    // e > 0 ?
                const unsigned int sel = up ? bb : (v >> 16);
                const float f = __uint_as_float(sel << 16);  // bf16 -> f32
                const float as = up ? A : C;
                const unsigned int bit = (unsigned int)(kmv >> (bsh + i)) & 1u;
                const float p = bit ? f * as : 0.f;
                pb[i] = __builtin_bit_cast(unsigned short, __float2bfloat16(p));
            }

            const bf16x8 af = __builtin_bit_cast(bf16x8, pb);
            #pragma unroll
            for (int qd = 0; qd < 4; ++qd) {
                const bf16x8 bq = __builtin_bit_cast(bf16x8, wq[qd]);
                acc[qd] = __builtin_amdgcn_mfma_f32_16x16x32_bf16(af, bq, acc[qd], 0, 0, 0);
            }
            accl = __builtin_amdgcn_mfma_f32_16x16x32_bf16(af, bones, accl, 0, 0, 0);
        }
    }

    // D layout: col = lane&15 (feature), row = 4*g + q
    if (r == 0) {
        #pragma unroll
        for (int q = 0; q < 4; ++q) l_lds[w * 16 + 4 * g + q] = accl[q];
    }
    #pragma unroll
    for (int q = 0; q < 4; ++q) {
        const int m = 4 * g + q;
        #pragma unroll
        for (int qd = 0; qd < 4; ++qd)
            acc_lds[(w * 16 + m) * OUTF + qd * 16 + r] = acc[qd][q];
    }
    __syncthreads();

    // merge partials across the 8 waves: 1024 outputs, 2 per thread
    {
        #pragma unroll
        for (int hh = 0; hh < 2; ++hh) {
            const int idx = t + hh * 512;
            const int row = idx >> 6;
            const int col = idx & 63;
            float L = 0.f, o = 0.f;
            #pragma unroll
            for (int ww = 0; ww < 8; ++ww) {
                L += l_lds[ww * 16 + row];
                o += acc_lds[(ww * 16 + row) * OUTF + col];
            }
            o /= L;
            o = (o > 0.f) ? o : expm1f(o); // ELU
            out[(size_t)(row_base + row) * OUTF + col] = o;
        }
    }
}

extern "C" void kernel_launch(void* const* d_in, const int* in_sizes, int n_in,
                              void* d_out, int out_size, void* d_ws, size_t ws_size,
                              hipStream_t stream) {
    const float* h = (const float*)d_in[0];
    const int* adj = (const int*)d_in[1];
    const float* W = (const float*)d_in[2];
    const float* a = (const float*)d_in[3];
    float* out = (float*)d_out;

    char* ws = (char*)d_ws;
    unsigned short* WhT = (unsigned short*)ws;                 // 1 MB
    unsigned short* WhTs = (unsigned short*)(ws + (1 << 20));  // 1 MB swizzled
    float* f1 = (float*)(ws + (2 << 20));                      // 32 KB
    float* f2 = f1 + NN;                                       // 32 KB
    float* f2m = f2 + NN;                                      // 4 B (pad 256)
    unsigned int* bd = (unsigned int*)((char*)f2m + 256);      // 32 KB
    unsigned char* bits = (unsigned char*)(ws + (4 << 20));    // 8 MB

    prep_kernel<<<NN / 32, 256, 0, stream>>>(h, W, a, WhT, f1, f2);
    fmax_kernel<<<1, 1024, 0, stream>>>(f2, f2m);
    bd_kernel<<<NN / 1024, 1024, 0, stream>>>(f2, bd);
    repack_kernel<<<NN / 32, 256, 0, stream>>>(WhT, WhTs);
    bitpack_kernel<<<NN, 256, 0, stream>>>(adj, bits);
    gatb_kernel<<<NN / 16, 512, 0, stream>>>(bits, WhTs, f1, bd, f2m, out);
}

// Round 21
// 76.574 us; speedup vs baseline: 1.2640x; 1.2640x over previous
//
#include <hip/hip_runtime.h>
#include <hip/hip_bf16.h>
#include <math.h>

#define NN 8192
#define INF_ 128
#define OUTF 64

typedef __attribute__((ext_vector_type(4))) float f32x4;
typedef __attribute__((ext_vector_type(2))) int i32x2;
typedef __attribute__((ext_vector_type(8))) unsigned short u16x8;
typedef __attribute__((ext_vector_type(8))) __bf16 bf16x8;

// barrier WITHOUT vmcnt drain: LDS visibility only (lgkmcnt).
#define BAR()                                                    \
    {                                                            \
        asm volatile("s_waitcnt lgkmcnt(0)" ::: "memory");       \
        __builtin_amdgcn_s_barrier();                            \
    }

__device__ __forceinline__ unsigned short f2bf(float f) {
    unsigned int u = __float_as_uint(f);
    u = (u + 0x7FFFu + ((u >> 16) & 1u)) >> 16;
    return (unsigned short)u;
}

// ---- Kernel 1: Wh = h@W (fp32); f1 = Wh@a1; f2 = Wh@a2; WhT = bf16(Wh)^T [64][8192]
__global__ __launch_bounds__(256) void prep_kernel(
    const float* __restrict__ h, const float* __restrict__ W,
    const float* __restrict__ a, unsigned short* __restrict__ WhT,
    float* __restrict__ f1, float* __restrict__ f2)
{
    __shared__ float W_lds[INF_ * OUTF];
    __shared__ float h_lds[32 * INF_];
    __shared__ unsigned short t_lds[OUTF * 34];

    const int t = threadIdx.x;
    const int rb = blockIdx.x * 32;

    {
        const float4* Ws = (const float4*)W;
        float4* Wd = (float4*)W_lds;
        #pragma unroll
        for (int q = 0; q < 8; ++q) Wd[t + 256 * q] = Ws[t + 256 * q];
        const float4* hs = (const float4*)(h + (size_t)rb * INF_);
        float4* hd = (float4*)h_lds;
        #pragma unroll
        for (int q = 0; q < 4; ++q) hd[t + 256 * q] = hs[t + 256 * q];
    }
    __syncthreads();

    const int lane = t & 63;
    const int w = t >> 6;

    float acc[8];
    #pragma unroll
    for (int q = 0; q < 8; ++q) acc[q] = 0.f;
    for (int k = 0; k < INF_; ++k) {
        const float wv = W_lds[k * OUTF + lane];
        #pragma unroll
        for (int q = 0; q < 8; ++q)
            acc[q] = fmaf(h_lds[(w * 8 + q) * INF_ + k], wv, acc[q]);
    }

    const float a1 = a[lane];
    const float a2 = a[OUTF + lane];
    #pragma unroll
    for (int q = 0; q < 8; ++q) {
        float s1 = acc[q] * a1;
        float s2 = acc[q] * a2;
        #pragma unroll
        for (int m = 1; m < 64; m <<= 1) {
            s1 += __shfl_xor(s1, m, 64);
            s2 += __shfl_xor(s2, m, 64);
        }
        if (lane == 0) {
            f1[rb + w * 8 + q] = s1;
            f2[rb + w * 8 + q] = s2;
        }
        t_lds[lane * 34 + w * 8 + q] = f2bf(acc[q]);
    }
    __syncthreads();
    {
        const int c = t >> 2;
        const int ro = (t & 3) * 8;
        unsigned int pk[4];
        #pragma unroll
        for (int i = 0; i < 4; ++i) {
            const unsigned int lo = t_lds[c * 34 + ro + 2 * i];
            const unsigned int hi = t_lds[c * 34 + ro + 2 * i + 1];
            pk[i] = lo | (hi << 16);
        }
        *(uint4*)(WhT + (size_t)c * NN + rb + ro) = make_uint4(pk[0], pk[1], pk[2], pk[3]);
    }
}

// ---- Kernel 1b: f2max = max_j f2[j]
__global__ __launch_bounds__(1024) void fmax_kernel(
    const float* __restrict__ f2, float* __restrict__ f2max)
{
    __shared__ float red[16];
    const int t = threadIdx.x;
    float m = -INFINITY;
    #pragma unroll
    for (int q = 0; q < NN / 1024; ++q) m = fmaxf(m, f2[t + q * 1024]);
    #pragma unroll
    for (int s = 1; s < 64; s <<= 1) m = fmaxf(m, __shfl_xor(m, s, 64));
    if ((t & 63) == 0) red[t >> 6] = m;
    __syncthreads();
    if (t == 0) {
        float r = red[0];
        #pragma unroll
        for (int i = 1; i < 16; ++i) r = fmaxf(r, red[i]);
        f2max[0] = r;
    }
}

// ---- Kernel 1c: repack WhT into lane-contiguous B-fragments.
__global__ __launch_bounds__(256) void repack_kernel(
    const unsigned short* __restrict__ WhT, unsigned short* __restrict__ WhTs)
{
    const int ch = blockIdx.x;    // 256 chunks of 32 j
    const int t = threadIdx.x;
    const int qd = t >> 6, l = t & 63;
    const int r = l & 15, g = l >> 4;
    const u16x8 v = *(const u16x8*)(WhT + (size_t)(qd * 16 + r) * NN + ch * 32 + g * 8);
    *(u16x8*)(WhTs + (size_t)ch * 2048 + qd * 512 + l * 8) = v;
}

// ---- Kernel 1d: bd[j] = pack(bf16(exp(f2_j)), bf16(exp(0.2*f2_j)))
__global__ __launch_bounds__(1024) void bd_kernel(
    const float* __restrict__ f2, unsigned int* __restrict__ bd)
{
    const int i = blockIdx.x * 1024 + threadIdx.x;
    const float v = f2[i];
    const unsigned int B = f2bf(expf(v));
    const unsigned int D = f2bf(expf(0.2f * v));
    bd[i] = B | (D << 16);
}

// ---- Kernel 2: monolithic-wave fusion (r12 structure) with exp-free consume:
//      p_ij = (e>0 ? A_i*B_j : C_i*D_j), tables bf16 in LDS, branch via u16 cmp.
__global__ __launch_bounds__(512) void gatz_kernel(
    const int* __restrict__ adj, const unsigned short* __restrict__ WhTs,
    const float* __restrict__ f1, const unsigned int* __restrict__ bd,
    const float* __restrict__ f2max, float* __restrict__ out)
{
    __shared__ float acc_lds[8 * 16 * OUTF];  // 32 KB partials
    __shared__ unsigned int bd_lds[NN];       // 32 KB (B,D) bf16 pairs
    __shared__ float l_lds[8 * 16];

    const int t = threadIdx.x;
    const int lane = t & 63;
    const int w = t >> 6;
    const int r = lane & 15;     // A-frag row / D feature
    const int g = lane >> 4;     // k-group
    const int row_base = blockIdx.x * 16;

    // stage bd (32 KB) cooperatively
    #pragma unroll
    for (int q = 0; q < 4; ++q)
        ((uint4*)bd_lds)[t + 512 * q] = ((const uint4*)bd)[t + 512 * q];

    const float f1r = f1[row_base + r];
    float Mr = f1r + f2max[0];
    Mr = fmaxf(Mr, 0.2f * Mr);
    const float A = expf(f1r - Mr);          // e>0 branch row factor
    const float C = expf(0.2f * f1r - Mr);   // e<=0 branch row factor
    const unsigned int THb = (unsigned int)f2bf(expf(-f1r)); // B_j > THb <=> e > 0

    f32x4 accl = {0.f, 0.f, 0.f, 0.f};
    f32x4 acc[4];
    #pragma unroll
    for (int q = 0; q < 4; ++q) acc[q] = accl;

    u16x8 ones_u;
    #pragma unroll
    for (int i = 0; i < 8; ++i) ones_u[i] = 0x3F80;
    const bf16x8 bones = __builtin_bit_cast(bf16x8, ones_u);

    // wave w owns j-window [w*1024, w*1024+1024), all 16 rows.
    const int j0 = w * 1024;
    const int* base = adj + (size_t)row_base * NN + j0 + 2 * lane;
    const u16x8* wv = (const u16x8*)WhTs + lane; // + (ch*4+qd)*64

    // stage seg 0: 16 rows x 128 j, lane-contiguous i32x2
    i32x2 st[16];
    #pragma unroll
    for (int rr = 0; rr < 16; ++rr)
        st[rr] = *(const i32x2*)(base + (size_t)rr * NN);

    BAR(); // bd_lds visible; adj loads stay in flight

    for (int s = 0; s < 8; ++s) {
        // ballot transpose: lane keeps the 2x64-bit masks of ITS row r.
        unsigned long long k0 = 0ull, k1 = 0ull;
        #pragma unroll
        for (int rr = 0; rr < 16; ++rr) {
            const i32x2 v = st[rr];
            const unsigned long long b0 = __ballot(v[0] > 0);
            const unsigned long long b1 = __ballot(v[1] > 0);
            if (rr == r) { k0 = b0; k1 = b1; }
        }
        // issue next segment's loads; they fly during the consume below
        if (s + 1 < 8) {
            #pragma unroll
            for (int rr = 0; rr < 16; ++rr)
                st[rr] = *(const i32x2*)(base + (size_t)rr * NN + (s + 1) * 128);
        }
        // consume 4 chunks of 32 j — exp-free table path
        #pragma unroll
        for (int cc = 0; cc < 4; ++cc) {
            const int jl = s * 128 + cc * 32;    // within wave window
            const int col = j0 + jl + g * 8;
            const int ch = (j0 + jl) >> 5;       // global 32-j chunk id
            const unsigned int sh = 16 * cc + 4 * g;
            const unsigned int m0 = (unsigned int)(k0 >> sh) & 0xFu; // even i
            const unsigned int m1 = (unsigned int)(k1 >> sh) & 0xFu; // odd  i
            const uint4 bq0 = *(const uint4*)(bd_lds + col);
            const uint4 bq1 = *(const uint4*)(bd_lds + col + 4);
            const unsigned int bdv[8] = {bq0.x, bq0.y, bq0.z, bq0.w,
                                         bq1.x, bq1.y, bq1.z, bq1.w};

            u16x8 pb;
            #pragma unroll
            for (int i = 0; i < 8; ++i) {
                const unsigned int v = bdv[i];
                const unsigned int bb = v & 0xFFFFu;
                const bool up = bb > THb;                    // e > 0 ?
                const unsigned int sel = up ? bb : (v >> 16);
                const float f = __uint_as_float(sel << 16);  // bf16 -> f32
                const float as = up ? A : C;
                const unsigned int bit = (((i & 1) ? m1 : m0) >> (i >> 1)) & 1u;
                const float p = bit ? f * as : 0.f;
                pb[i] = __builtin_bit_cast(unsigned short, __float2bfloat16(p));
            }

            const bf16x8 af = __builtin_bit_cast(bf16x8, pb);
            #pragma unroll
            for (int qd = 0; qd < 4; ++qd) {
                const bf16x8 bq = __builtin_bit_cast(bf16x8, wv[((size_t)ch * 4 + qd) * 64]);
                acc[qd] = __builtin_amdgcn_mfma_f32_16x16x32_bf16(af, bq, acc[qd], 0, 0, 0);
            }
            accl = __builtin_amdgcn_mfma_f32_16x16x32_bf16(af, bones, accl, 0, 0, 0);
        }
    }

    // D layout: col = lane&15 (feature), row = 4*g + q
    if (r == 0) {
        #pragma unroll
        for (int q = 0; q < 4; ++q) l_lds[w * 16 + 4 * g + q] = accl[q];
    }
    #pragma unroll
    for (int q = 0; q < 4; ++q) {
        const int m = 4 * g + q;
        #pragma unroll
        for (int qd = 0; qd < 4; ++qd)
            acc_lds[(w * 16 + m) * OUTF + qd * 16 + r] = acc[qd][q];
    }
    __syncthreads();

    // merge partials across the 8 waves: 1024 outputs, 2 per thread
    {
        #pragma unroll
        for (int hh = 0; hh < 2; ++hh) {
            const int idx = t + hh * 512;
            const int row = idx >> 6;
            const int col = idx & 63;
            float L = 0.f, o = 0.f;
            #pragma unroll
            for (int ww = 0; ww < 8; ++ww) {
                L += l_lds[ww * 16 + row];
                o += acc_lds[(ww * 16 + row) * OUTF + col];
            }
            o /= L;
            o = (o > 0.f) ? o : expm1f(o); // ELU
            out[(size_t)(row_base + row) * OUTF + col] = o;
        }
    }
}

extern "C" void kernel_launch(void* const* d_in, const int* in_sizes, int n_in,
                              void* d_out, int out_size, void* d_ws, size_t ws_size,
                              hipStream_t stream) {
    const float* h = (const float*)d_in[0];
    const int* adj = (const int*)d_in[1];
    const float* W = (const float*)d_in[2];
    const float* a = (const float*)d_in[3];
    float* out = (float*)d_out;

    char* ws = (char*)d_ws;
    unsigned short* WhT = (unsigned short*)ws;                 // 1 MB
    unsigned short* WhTs = (unsigned short*)(ws + (1 << 20));  // 1 MB swizzled
    float* f1 = (float*)(ws + (2 << 20));                      // 32 KB
    float* f2 = f1 + NN;                                       // 32 KB
    float* f2m = f2 + NN;                                      // 4 B
    unsigned int* bd = (unsigned int*)(f2m + 64);              // 32 KB

    prep_kernel<<<NN / 32, 256, 0, stream>>>(h, W, a, WhT, f1, f2);
    fmax_kernel<<<1, 1024, 0, stream>>>(f2, f2m);
    bd_kernel<<<NN / 1024, 1024, 0, stream>>>(f2, bd);
    repack_kernel<<<NN / 32, 256, 0, stream>>>(WhT, WhTs);
    gatz_kernel<<<NN / 16, 512, 0, stream>>>(adj, WhTs, f1, bd, f2m, out);
}

// Round 22
// 73.577 us; speedup vs baseline: 1.3155x; 1.0407x over previous
//
#include <hip/hip_runtime.h>
#include <hip/hip_bf16.h>
#include <math.h>

#define NN 8192
#define INF_ 128
#define OUTF 64

typedef __attribute__((ext_vector_type(4))) float f32x4;
typedef __attribute__((ext_vector_type(2))) int i32x2;
typedef __attribute__((ext_vector_type(8))) unsigned short u16x8;
typedef __attribute__((ext_vector_type(8))) __bf16 bf16x8;

// barrier WITHOUT vmcnt drain: LDS visibility only (lgkmcnt).
#define BAR()                                                    \
    {                                                            \
        asm volatile("s_waitcnt lgkmcnt(0)" ::: "memory");       \
        __builtin_amdgcn_s_barrier();                            \
    }

__device__ __forceinline__ unsigned short f2bf(float f) {
    unsigned int u = __float_as_uint(f);
    u = (u + 0x7FFFu + ((u >> 16) & 1u)) >> 16;
    return (unsigned short)u;
}

// ---- Kernel 1 (FUSED): Wh = h@W; f1, f2; bd = pack(exp(f2), exp(0.2 f2));
//      WhTs (lane-contiguous B-fragments) written directly from t_lds.
//      Block rb covers nodes [rb, rb+32) == WhTs chunk ch = rb/32.
__global__ __launch_bounds__(256) void prep_kernel(
    const float* __restrict__ h, const float* __restrict__ W,
    const float* __restrict__ a, unsigned short* __restrict__ WhTs,
    float* __restrict__ f1, float* __restrict__ f2,
    unsigned int* __restrict__ bd)
{
    __shared__ float W_lds[INF_ * OUTF];
    __shared__ float h_lds[32 * INF_];
    __shared__ unsigned short t_lds[OUTF * 34];

    const int t = threadIdx.x;
    const int rb = blockIdx.x * 32;

    {
        const float4* Ws = (const float4*)W;
        float4* Wd = (float4*)W_lds;
        #pragma unroll
        for (int q = 0; q < 8; ++q) Wd[t + 256 * q] = Ws[t + 256 * q];
        const float4* hs = (const float4*)(h + (size_t)rb * INF_);
        float4* hd = (float4*)h_lds;
        #pragma unroll
        for (int q = 0; q < 4; ++q) hd[t + 256 * q] = hs[t + 256 * q];
    }
    __syncthreads();

    const int lane = t & 63;
    const int w = t >> 6;

    float acc[8];
    #pragma unroll
    for (int q = 0; q < 8; ++q) acc[q] = 0.f;
    for (int k = 0; k < INF_; ++k) {
        const float wv = W_lds[k * OUTF + lane];
        #pragma unroll
        for (int q = 0; q < 8; ++q)
            acc[q] = fmaf(h_lds[(w * 8 + q) * INF_ + k], wv, acc[q]);
    }

    const float a1 = a[lane];
    const float a2 = a[OUTF + lane];
    #pragma unroll
    for (int q = 0; q < 8; ++q) {
        float s1 = acc[q] * a1;
        float s2 = acc[q] * a2;
        #pragma unroll
        for (int m = 1; m < 64; m <<= 1) {
            s1 += __shfl_xor(s1, m, 64);
            s2 += __shfl_xor(s2, m, 64);
        }
        if (lane == 0) {
            f1[rb + w * 8 + q] = s1;
            f2[rb + w * 8 + q] = s2;
            const unsigned int Bv = f2bf(expf(s2));
            const unsigned int Dv = f2bf(expf(0.2f * s2));
            bd[rb + w * 8 + q] = Bv | (Dv << 16);   // fused bd_kernel
        }
        t_lds[lane * 34 + w * 8 + q] = f2bf(acc[q]);
    }
    __syncthreads();
    {
        // fused repack: WhTs[ch*2048 + qd*512 + l*8 + e]
        //   = WhT[qd*16 + (l&15)][ch*32 + (l>>4)*8 + e]
        //   = t_lds[(qd*16 + (l&15))*34 + (l>>4)*8 + e]
        const int qd = t >> 6, l = t & 63;
        const int c = qd * 16 + (l & 15);
        const int jr0 = (l >> 4) * 8;
        u16x8 v;
        #pragma unroll
        for (int e = 0; e < 8; ++e) v[e] = t_lds[c * 34 + jr0 + e];
        *(u16x8*)(WhTs + (size_t)blockIdx.x * 2048 + qd * 512 + l * 8) = v;
    }
}

// ---- Kernel 1b: f2max = max_j f2[j]
__global__ __launch_bounds__(1024) void fmax_kernel(
    const float* __restrict__ f2, float* __restrict__ f2max)
{
    __shared__ float red[16];
    const int t = threadIdx.x;
    float m = -INFINITY;
    #pragma unroll
    for (int q = 0; q < NN / 1024; ++q) m = fmaxf(m, f2[t + q * 1024]);
    #pragma unroll
    for (int s = 1; s < 64; s <<= 1) m = fmaxf(m, __shfl_xor(m, s, 64));
    if ((t & 63) == 0) red[t >> 6] = m;
    __syncthreads();
    if (t == 0) {
        float r = red[0];
        #pragma unroll
        for (int i = 1; i < 16; ++i) r = fmaxf(r, red[i]);
        f2max[0] = r;
    }
}

// ---- Kernel 2: monolithic-wave fusion (r14/r21 proven, byte-identical):
//      p_ij = (e>0 ? A_i*B_j : C_i*D_j), tables bf16 in LDS, branch via u16 cmp.
__global__ __launch_bounds__(512) void gatz_kernel(
    const int* __restrict__ adj, const unsigned short* __restrict__ WhTs,
    const float* __restrict__ f1, const unsigned int* __restrict__ bd,
    const float* __restrict__ f2max, float* __restrict__ out)
{
    __shared__ float acc_lds[8 * 16 * OUTF];  // 32 KB partials
    __shared__ unsigned int bd_lds[NN];       // 32 KB (B,D) bf16 pairs
    __shared__ float l_lds[8 * 16];

    const int t = threadIdx.x;
    const int lane = t & 63;
    const int w = t >> 6;
    const int r = lane & 15;     // A-frag row / D feature
    const int g = lane >> 4;     // k-group
    const int row_base = blockIdx.x * 16;

    // stage bd (32 KB) cooperatively
    #pragma unroll
    for (int q = 0; q < 4; ++q)
        ((uint4*)bd_lds)[t + 512 * q] = ((const uint4*)bd)[t + 512 * q];

    const float f1r = f1[row_base + r];
    float Mr = f1r + f2max[0];
    Mr = fmaxf(Mr, 0.2f * Mr);
    const float A = expf(f1r - Mr);          // e>0 branch row factor
    const float C = expf(0.2f * f1r - Mr);   // e<=0 branch row factor
    const unsigned int THb = (unsigned int)f2bf(expf(-f1r)); // B_j > THb <=> e > 0

    f32x4 accl = {0.f, 0.f, 0.f, 0.f};
    f32x4 acc[4];
    #pragma unroll
    for (int q = 0; q < 4; ++q) acc[q] = accl;

    u16x8 ones_u;
    #pragma unroll
    for (int i = 0; i < 8; ++i) ones_u[i] = 0x3F80;
    const bf16x8 bones = __builtin_bit_cast(bf16x8, ones_u);

    // wave w owns j-window [w*1024, w*1024+1024), all 16 rows.
    const int j0 = w * 1024;
    const int* base = adj + (size_t)row_base * NN + j0 + 2 * lane;
    const u16x8* wv = (const u16x8*)WhTs + lane; // + (ch*4+qd)*64

    // stage seg 0: 16 rows x 128 j, lane-contiguous i32x2
    i32x2 st[16];
    #pragma unroll
    for (int rr = 0; rr < 16; ++rr)
        st[rr] = *(const i32x2*)(base + (size_t)rr * NN);

    BAR(); // bd_lds visible; adj loads stay in flight

    for (int s = 0; s < 8; ++s) {
        // ballot transpose: lane keeps the 2x64-bit masks of ITS row r.
        unsigned long long k0 = 0ull, k1 = 0ull;
        #pragma unroll
        for (int rr = 0; rr < 16; ++rr) {
            const i32x2 v = st[rr];
            const unsigned long long b0 = __ballot(v[0] > 0);
            const unsigned long long b1 = __ballot(v[1] > 0);
            if (rr == r) { k0 = b0; k1 = b1; }
        }
        // issue next segment's loads; they fly during the consume below
        if (s + 1 < 8) {
            #pragma unroll
            for (int rr = 0; rr < 16; ++rr)
                st[rr] = *(const i32x2*)(base + (size_t)rr * NN + (s + 1) * 128);
        }
        // consume 4 chunks of 32 j — exp-free table path
        #pragma unroll
        for (int cc = 0; cc < 4; ++cc) {
            const int jl = s * 128 + cc * 32;    // within wave window
            const int col = j0 + jl + g * 8;
            const int ch = (j0 + jl) >> 5;       // global 32-j chunk id
            const unsigned int sh = 16 * cc + 4 * g;
            const unsigned int m0 = (unsigned int)(k0 >> sh) & 0xFu; // even i
            const unsigned int m1 = (unsigned int)(k1 >> sh) & 0xFu; // odd  i
            const uint4 bq0 = *(const uint4*)(bd_lds + col);
            const uint4 bq1 = *(const uint4*)(bd_lds + col + 4);
            const unsigned int bdv[8] = {bq0.x, bq0.y, bq0.z, bq0.w,
                                         bq1.x, bq1.y, bq1.z, bq1.w};

            u16x8 pb;
            #pragma unroll
            for (int i = 0; i < 8; ++i) {
                const unsigned int v = bdv[i];
                const unsigned int bb = v & 0xFFFFu;
                const bool up = bb > THb;                    // e > 0 ?
                const unsigned int sel = up ? bb : (v >> 16);
                const float f = __uint_as_float(sel << 16);  // bf16 -> f32
                const float as = up ? A : C;
                const unsigned int bit = (((i & 1) ? m1 : m0) >> (i >> 1)) & 1u;
                const float p = bit ? f * as : 0.f;
                pb[i] = __builtin_bit_cast(unsigned short, __float2bfloat16(p));
            }

            const bf16x8 af = __builtin_bit_cast(bf16x8, pb);
            #pragma unroll
            for (int qd = 0; qd < 4; ++qd) {
                const bf16x8 bq = __builtin_bit_cast(bf16x8, wv[((size_t)ch * 4 + qd) * 64]);
                acc[qd] = __builtin_amdgcn_mfma_f32_16x16x32_bf16(af, bq, acc[qd], 0, 0, 0);
            }
            accl = __builtin_amdgcn_mfma_f32_16x16x32_bf16(af, bones, accl, 0, 0, 0);
        }
    }

    // D layout: col = lane&15 (feature), row = 4*g + q
    if (r == 0) {
        #pragma unroll
        for (int q = 0; q < 4; ++q) l_lds[w * 16 + 4 * g + q] = accl[q];
    }
    #pragma unroll
    for (int q = 0; q < 4; ++q) {
        const int m = 4 * g + q;
        #pragma unroll
        for (int qd = 0; qd < 4; ++qd)
            acc_lds[(w * 16 + m) * OUTF + qd * 16 + r] = acc[qd][q];
    }
    __syncthreads();

    // merge partials across the 8 waves: 1024 outputs, 2 per thread
    {
        #pragma unroll
        for (int hh = 0; hh < 2; ++hh) {
            const int idx = t + hh * 512;
            const int row = idx >> 6;
            const int col = idx & 63;
            float L = 0.f, o = 0.f;
            #pragma unroll
            for (int ww = 0; ww < 8; ++ww) {
                L += l_lds[ww * 16 + row];
                o += acc_lds[(ww * 16 + row) * OUTF + col];
            }
            o /= L;
            o = (o > 0.f) ? o : expm1f(o); // ELU
            out[(size_t)(row_base + row) * OUTF + col] = o;
        }
    }
}

extern "C" void kernel_launch(void* const* d_in, const int* in_sizes, int n_in,
                              void* d_out, int out_size, void* d_ws, size_t ws_size,
                              hipStream_t stream) {
    const float* h = (const float*)d_in[0];
    const int* adj = (const int*)d_in[1];
    const float* W = (const float*)d_in[2];
    const float* a = (const float*)d_in[3];
    float* out = (float*)d_out;

    char* ws = (char*)d_ws;
    unsigned short* WhTs = (unsigned short*)ws;                // 1 MB (lane-contiguous)
    float* f1 = (float*)(ws + (1 << 20));                      // 32 KB
    float* f2 = f1 + NN;                                       // 32 KB
    float* f2m = f2 + NN;                                      // 4 B (pad 256)
    unsigned int* bd = (unsigned int*)((char*)f2m + 256);      // 32 KB

    prep_kernel<<<NN / 32, 256, 0, stream>>>(h, W, a, WhTs, f1, f2, bd);
    fmax_kernel<<<1, 1024, 0, stream>>>(f2, f2m);
    gatz_kernel<<<NN / 16, 512, 0, stream>>>(adj, WhTs, f1, bd, f2m, out);
}

// Round 23
// 71.908 us; speedup vs baseline: 1.3461x; 1.0232x over previous
//
#include <hip/hip_runtime.h>
#include <hip/hip_bf16.h>
#include <math.h>

#define NN 8192
#define INF_ 128
#define OUTF 64

typedef __attribute__((ext_vector_type(4))) float f32x4;
typedef __attribute__((ext_vector_type(2))) int i32x2;
typedef __attribute__((ext_vector_type(8))) unsigned short u16x8;
typedef __attribute__((ext_vector_type(8))) __bf16 bf16x8;

// barrier WITHOUT vmcnt drain: LDS visibility only (lgkmcnt).
#define BAR()                                                    \
    {                                                            \
        asm volatile("s_waitcnt lgkmcnt(0)" ::: "memory");       \
        __builtin_amdgcn_s_barrier();                            \
    }

__device__ __forceinline__ unsigned short f2bf(float f) {
    unsigned int u = __float_as_uint(f);
    u = (u + 0x7FFFu + ((u >> 16) & 1u)) >> 16;
    return (unsigned short)u;
}

// ---- Kernel 1 (FUSED): Wh = h@W; f1; bd = pack(exp(f2), exp(0.2 f2));
//      WhTs (lane-contiguous B-fragments) written directly from t_lds.
//      Block rb covers nodes [rb, rb+32) == WhTs chunk ch = rb/32.
__global__ __launch_bounds__(256) void prep_kernel(
    const float* __restrict__ h, const float* __restrict__ W,
    const float* __restrict__ a, unsigned short* __restrict__ WhTs,
    float* __restrict__ f1, unsigned int* __restrict__ bd)
{
    __shared__ float W_lds[INF_ * OUTF];
    __shared__ float h_lds[32 * INF_];
    __shared__ unsigned short t_lds[OUTF * 34];

    const int t = threadIdx.x;
    const int rb = blockIdx.x * 32;

    {
        const float4* Ws = (const float4*)W;
        float4* Wd = (float4*)W_lds;
        #pragma unroll
        for (int q = 0; q < 8; ++q) Wd[t + 256 * q] = Ws[t + 256 * q];
        const float4* hs = (const float4*)(h + (size_t)rb * INF_);
        float4* hd = (float4*)h_lds;
        #pragma unroll
        for (int q = 0; q < 4; ++q) hd[t + 256 * q] = hs[t + 256 * q];
    }
    __syncthreads();

    const int lane = t & 63;
    const int w = t >> 6;

    float acc[8];
    #pragma unroll
    for (int q = 0; q < 8; ++q) acc[q] = 0.f;
    for (int k = 0; k < INF_; ++k) {
        const float wv = W_lds[k * OUTF + lane];
        #pragma unroll
        for (int q = 0; q < 8; ++q)
            acc[q] = fmaf(h_lds[(w * 8 + q) * INF_ + k], wv, acc[q]);
    }

    const float a1 = a[lane];
    const float a2 = a[OUTF + lane];
    #pragma unroll
    for (int q = 0; q < 8; ++q) {
        float s1 = acc[q] * a1;
        float s2 = acc[q] * a2;
        #pragma unroll
        for (int m = 1; m < 64; m <<= 1) {
            s1 += __shfl_xor(s1, m, 64);
            s2 += __shfl_xor(s2, m, 64);
        }
        if (lane == 0) {
            f1[rb + w * 8 + q] = s1;
            const unsigned int Bv = f2bf(expf(s2));
            const unsigned int Dv = f2bf(expf(0.2f * s2));
            bd[rb + w * 8 + q] = Bv | (Dv << 16);   // fused bd_kernel
        }
        t_lds[lane * 34 + w * 8 + q] = f2bf(acc[q]);
    }
    __syncthreads();
    {
        // fused repack: WhTs[ch*2048 + qd*512 + l*8 + e]
        //   = t_lds[(qd*16 + (l&15))*34 + (l>>4)*8 + e]
        const int qd = t >> 6, l = t & 63;
        const int c = qd * 16 + (l & 15);
        const int jr0 = (l >> 4) * 8;
        u16x8 v;
        #pragma unroll
        for (int e = 0; e < 8; ++e) v[e] = t_lds[c * 34 + jr0 + e];
        *(u16x8*)(WhTs + (size_t)blockIdx.x * 2048 + qd * 512 + l * 8) = v;
    }
}

// ---- Kernel 2: monolithic-wave fusion. Mr dropped entirely: the softmax
//      ratio acc/L is scale-invariant per row, so A = exp(f1), C = exp(0.2 f1)
//      need no max subtraction (p <= ~e^40, safely in fp32/bf16 range).
__global__ __launch_bounds__(512) void gatz_kernel(
    const int* __restrict__ adj, const unsigned short* __restrict__ WhTs,
    const float* __restrict__ f1, const unsigned int* __restrict__ bd,
    float* __restrict__ out)
{
    __shared__ float acc_lds[8 * 16 * OUTF];  // 32 KB partials
    __shared__ unsigned int bd_lds[NN];       // 32 KB (B,D) bf16 pairs
    __shared__ float l_lds[8 * 16];

    const int t = threadIdx.x;
    const int lane = t & 63;
    const int w = t >> 6;
    const int r = lane & 15;     // A-frag row / D feature
    const int g = lane >> 4;     // k-group
    const int row_base = blockIdx.x * 16;

    // stage bd (32 KB) cooperatively
    #pragma unroll
    for (int q = 0; q < 4; ++q)
        ((uint4*)bd_lds)[t + 512 * q] = ((const uint4*)bd)[t + 512 * q];

    const float f1r = f1[row_base + r];
    const float A = expf(f1r);               // e>0 branch row factor
    const float C = expf(0.2f * f1r);        // e<=0 branch row factor
    const unsigned int THb = (unsigned int)f2bf(expf(-f1r)); // B_j > THb <=> e > 0

    f32x4 accl = {0.f, 0.f, 0.f, 0.f};
    f32x4 acc[4];
    #pragma unroll
    for (int q = 0; q < 4; ++q) acc[q] = accl;

    u16x8 ones_u;
    #pragma unroll
    for (int i = 0; i < 8; ++i) ones_u[i] = 0x3F80;
    const bf16x8 bones = __builtin_bit_cast(bf16x8, ones_u);

    // wave w owns j-window [w*1024, w*1024+1024), all 16 rows.
    const int j0 = w * 1024;
    const int* base = adj + (size_t)row_base * NN + j0 + 2 * lane;
    const u16x8* wv = (const u16x8*)WhTs + lane; // + (ch*4+qd)*64

    // stage seg 0: 16 rows x 128 j, lane-contiguous i32x2
    i32x2 st[16];
    #pragma unroll
    for (int rr = 0; rr < 16; ++rr)
        st[rr] = *(const i32x2*)(base + (size_t)rr * NN);

    BAR(); // bd_lds visible; adj loads stay in flight

    for (int s = 0; s < 8; ++s) {
        // ballot transpose: lane keeps the 2x64-bit masks of ITS row r.
        unsigned long long k0 = 0ull, k1 = 0ull;
        #pragma unroll
        for (int rr = 0; rr < 16; ++rr) {
            const i32x2 v = st[rr];
            const unsigned long long b0 = __ballot(v[0] > 0);
            const unsigned long long b1 = __ballot(v[1] > 0);
            if (rr == r) { k0 = b0; k1 = b1; }
        }
        // issue next segment's loads; they fly during the consume below
        if (s + 1 < 8) {
            #pragma unroll
            for (int rr = 0; rr < 16; ++rr)
                st[rr] = *(const i32x2*)(base + (size_t)rr * NN + (s + 1) * 128);
        }
        // consume 4 chunks of 32 j — exp-free table path
        #pragma unroll
        for (int cc = 0; cc < 4; ++cc) {
            const int jl = s * 128 + cc * 32;    // within wave window
            const int col = j0 + jl + g * 8;
            const int ch = (j0 + jl) >> 5;       // global 32-j chunk id
            const unsigned int sh = 16 * cc + 4 * g;
            const unsigned int m0 = (unsigned int)(k0 >> sh) & 0xFu; // even i
            const unsigned int m1 = (unsigned int)(k1 >> sh) & 0xFu; // odd  i
            const uint4 bq0 = *(const uint4*)(bd_lds + col);
            const uint4 bq1 = *(const uint4*)(bd_lds + col + 4);
            const unsigned int bdv[8] = {bq0.x, bq0.y, bq0.z, bq0.w,
                                         bq1.x, bq1.y, bq1.z, bq1.w};

            u16x8 pb;
            #pragma unroll
            for (int i = 0; i < 8; ++i) {
                const unsigned int v = bdv[i];
                const unsigned int bb = v & 0xFFFFu;
                const bool up = bb > THb;                    // e > 0 ?
                const unsigned int sel = up ? bb : (v >> 16);
                const float f = __uint_as_float(sel << 16);  // bf16 -> f32
                const float as = up ? A : C;
                const unsigned int bit = (((i & 1) ? m1 : m0) >> (i >> 1)) & 1u;
                const float p = bit ? f * as : 0.f;
                pb[i] = __builtin_bit_cast(unsigned short, __float2bfloat16(p));
            }

            const bf16x8 af = __builtin_bit_cast(bf16x8, pb);
            #pragma unroll
            for (int qd = 0; qd < 4; ++qd) {
                const bf16x8 bq = __builtin_bit_cast(bf16x8, wv[((size_t)ch * 4 + qd) * 64]);
                acc[qd] = __builtin_amdgcn_mfma_f32_16x16x32_bf16(af, bq, acc[qd], 0, 0, 0);
            }
            accl = __builtin_amdgcn_mfma_f32_16x16x32_bf16(af, bones, accl, 0, 0, 0);
        }
    }

    // D layout: col = lane&15 (feature), row = 4*g + q
    if (r == 0) {
        #pragma unroll
        for (int q = 0; q < 4; ++q) l_lds[w * 16 + 4 * g + q] = accl[q];
    }
    #pragma unroll
    for (int q = 0; q < 4; ++q) {
        const int m = 4 * g + q;
        #pragma unroll
        for (int qd = 0; qd < 4; ++qd)
            acc_lds[(w * 16 + m) * OUTF + qd * 16 + r] = acc[qd][q];
    }
    __syncthreads();

    // merge partials across the 8 waves: 1024 outputs, 2 per thread
    {
        #pragma unroll
        for (int hh = 0; hh < 2; ++hh) {
            const int idx = t + hh * 512;
            const int row = idx >> 6;
            const int col = idx & 63;
            float L = 0.f, o = 0.f;
            #pragma unroll
            for (int ww = 0; ww < 8; ++ww) {
                L += l_lds[ww * 16 + row];
                o += acc_lds[(ww * 16 + row) * OUTF + col];
            }
            o /= L;
            o = (o > 0.f) ? o : expm1f(o); // ELU
            out[(size_t)(row_base + row) * OUTF + col] = o;
        }
    }
}

extern "C" void kernel_launch(void* const* d_in, const int* in_sizes, int n_in,
                              void* d_out, int out_size, void* d_ws, size_t ws_size,
                              hipStream_t stream) {
    const float* h = (const float*)d_in[0];
    const int* adj = (const int*)d_in[1];
    const float* W = (const float*)d_in[2];
    const float* a = (const float*)d_in[3];
    float* out = (float*)d_out;

    char* ws = (char*)d_ws;
    unsigned short* WhTs = (unsigned short*)ws;                // 1 MB (lane-contiguous)
    float* f1 = (float*)(ws + (1 << 20));                      // 32 KB
    unsigned int* bd = (unsigned int*)(f1 + NN);               // 32 KB

    prep_kernel<<<NN / 32, 256, 0, stream>>>(h, W, a, WhTs, f1, bd);
    gatz_kernel<<<NN / 16, 512, 0, stream>>>(adj, WhTs, f1, bd, out);
}